// Round 13
// baseline (22.585 us; speedup 1.0000x reference)
//
#include <hip/hip_runtime.h>
#include <math.h>

#define DD       768
#define HDIM     512
#define TOKDIM   256
#define LOCALDIM 16384
#define FEATDIM  16640            // 16384 + 256
#define BB       64
#define THRESH   0.7f
#define ONEF     0x3f800000u      // bit pattern of 1.0f
#define UC       8                // unit chunks of 64
#define UNITS    64
#define BPG      2                // batches per group; 32 bgroups x 8 uc = 256 blocks

// NetVLAD local branch is identically 1.0 (softmax(axis=1).sum(axis=1) == 1),
// so feats = [inv * ones(16384), g/norm], norm = sqrt(16384 + ||g||^2), and
// sim_ij = (16384 + g_i.g_j) * inv_i * inv_j.

// ---- K_A: 256 blocks = 32 batch-pairs x 8 unit-chunks. Full-d layer-1 for
// 64 units (in-block fold + bias + ReLU) then layer-2 partial g, accumulated
// straight into g[64][256] via HW float atomics (buffer zeroed per launch).
// Atomic-order nondeterminism is ~1e-6 — 4 orders below the 2e-2 threshold.
__global__ __launch_bounds__(1024) void kA(
    const float* __restrict__ gtok, const float* __restrict__ W1,
    const float* __restrict__ b1,   const float* __restrict__ W2,
    float* __restrict__ g,          unsigned* __restrict__ maskU)
{
    __shared__ float  xs[BPG][DD];     // 6 KB
    __shared__ float4 buf[2112];       // 33.8 KB: hh[64][33] f4, then gg[16][129] f4
    __shared__ float  pr[1024];        // 4 KB fold stage
    __shared__ float  hs[BPG][UNITS];  // post-ReLU h slice
    const int blk = blockIdx.x, t = threadIdx.x;
    const int bg = blk >> 3, uc = blk & 7;
    const int b0 = bg * BPG, u0 = uc * UNITS;

    if (blk == 0) {                    // zero mask; graph edge orders before kB
        maskU[t] = 0u; maskU[t+1024] = 0u; maskU[t+2048] = 0u; maskU[t+3072] = 0u;
    }
    for (int i = t; i < BPG * DD; i += 1024)
        xs[i / DD][i % DD] = gtok[(size_t)(b0 + i / DD) * DD + (i % DD)];
    __syncthreads();

    // layer 1: thread = (u4 = t&15 -> 4 units, q = t>>4 -> 12-d slice), 2 batches
    {
        const int u4 = t & 15, q = t >> 4, d0 = q * 12;
        const float4* w = (const float4*)W1 + (size_t)d0 * 128 + uc * 16 + u4;
        float4 a0 = {0,0,0,0}, a1 = {0,0,0,0};
        #pragma unroll
        for (int d = 0; d < 12; ++d) {
            const float4 wv = w[(size_t)d * 128];
            const float x0 = xs[0][d0+d], x1 = xs[1][d0+d];
            a0.x = fmaf(x0, wv.x, a0.x); a0.y = fmaf(x0, wv.y, a0.y);
            a0.z = fmaf(x0, wv.z, a0.z); a0.w = fmaf(x0, wv.w, a0.w);
            a1.x = fmaf(x1, wv.x, a1.x); a1.y = fmaf(x1, wv.y, a1.y);
            a1.z = fmaf(x1, wv.z, a1.z); a1.w = fmaf(x1, wv.w, a1.w);
        }
        buf[q * 33 + u4 * 2 + 0] = a0;     // hh[q][u4*2+bb], pad stride 33
        buf[q * 33 + u4 * 2 + 1] = a1;
    }
    __syncthreads();
    {   // fold 64 q -> 8 (col c = u4*8 + bb*4 + comp; float stride 132)
        const float* hf = (const float*)buf;
        const int c = t & 127, qg = t >> 7;
        float s = 0.f;
        #pragma unroll
        for (int qq = 0; qq < 8; ++qq) s += hf[(size_t)(qg*8+qq)*132 + c];
        pr[qg * 128 + c] = s;
    }
    __syncthreads();
    if (t < 128) {                     // c=t -> u = (c>>3)*4 + (c&3), bb = (c>>2)&1
        const int u = ((t >> 3) << 2) | (t & 3), bb = (t >> 2) & 1;
        float s = b1[u0 + u];
        #pragma unroll
        for (int qg = 0; qg < 8; ++qg) s += pr[qg * 128 + t];
        hs[bb][u] = fmaxf(s, 0.f);
    }
    __syncthreads();

    // layer 2 partial: thread = (o4 = t&63 -> 4 outs, jq = t>>6 -> 4 units)
    {
        const int o4 = t & 63, jq = t >> 6;
        const float4* w = (const float4*)W2 + (size_t)(u0 + jq * 4) * 64 + o4;
        float4 a0 = {0,0,0,0}, a1 = {0,0,0,0};
        #pragma unroll
        for (int jj = 0; jj < 4; ++jj) {
            const float4 wv = w[(size_t)jj * 64];
            const float h0 = hs[0][jq*4+jj], h1 = hs[1][jq*4+jj];
            a0.x = fmaf(h0, wv.x, a0.x); a0.y = fmaf(h0, wv.y, a0.y);
            a0.z = fmaf(h0, wv.z, a0.z); a0.w = fmaf(h0, wv.w, a0.w);
            a1.x = fmaf(h1, wv.x, a1.x); a1.y = fmaf(h1, wv.y, a1.y);
            a1.z = fmaf(h1, wv.z, a1.z); a1.w = fmaf(h1, wv.w, a1.w);
        }
        buf[jq * 129 + o4 * 2 + 0] = a0;   // gg[jq][o4*2+bb], pad stride 129
        buf[jq * 129 + o4 * 2 + 1] = a1;
    }
    __syncthreads();
    {   // fold 16 jq -> 2 (col c = o4*8 + bb*4 + comp; float stride 516)
        const float* gf = (const float*)buf;
        const int c = t & 511, qg = t >> 9;
        float s = 0.f;
        #pragma unroll
        for (int qq = 0; qq < 8; ++qq) s += gf[(size_t)(qg*8+qq)*516 + c];
        pr[qg * 512 + c] = s;
    }
    __syncthreads();
    if (t < 512) {                     // b2 added once in kB
        const int o = ((t >> 3) << 2) | (t & 3), bb = (t >> 2) & 1;
        unsafeAtomicAdd(&g[(size_t)(b0 + bb) * TOKDIM + o], pr[t] + pr[512 + t]);
    }
}

// ---- K_B: 64 blocks. Block i: load finished g (64 KB, L2-hot) + b2 into
// gT, all inv-norms, feats row i (fill + gn), sim row i, top-k, mask ORs. ----
__global__ __launch_bounds__(1024) void kB(
    const float* __restrict__ g, const float* __restrict__ b2,
    const int* __restrict__ kptr, float* __restrict__ feats,
    unsigned* __restrict__ maskU)
{
    __shared__ float gT[TOKDIM][BB + 1];   // stride 65: conflict-free both ways
    __shared__ float part[16][BB];
    __shared__ float invs[BB];
    const int i = blockIdx.x, t = threadIdx.x;
    const float4* g4  = (const float4*)g;
    const float4* b24 = (const float4*)b2;

    #pragma unroll
    for (int r = 0; r < 4; ++r) {          // f indexes [64 j][64 d4] float4
        const int f = r * 1024 + t, j = f >> 6, d4 = f & 63;
        const float4 v = g4[f], bv = b24[d4];
        gT[d4*4+0][j] = v.x + bv.x; gT[d4*4+1][j] = v.y + bv.y;
        gT[d4*4+2][j] = v.z + bv.z; gT[d4*4+3][j] = v.w + bv.w;
    }
    __syncthreads();

    {   // ||g_j||^2 partials
        const int q = t >> 6, j = t & 63;
        float s = 0.f;
        #pragma unroll
        for (int dd = 0; dd < 16; ++dd) { const float v = gT[q*16+dd][j]; s = fmaf(v, v, s); }
        part[q][j] = s;
    }
    __syncthreads();
    if (t < BB) {
        float ssq = 0.f;
        #pragma unroll
        for (int q = 0; q < 16; ++q) ssq += part[q][t];
        invs[t] = 1.f / fmaxf(sqrtf((float)LOCALDIM + ssq), 1e-12f);
    }
    __syncthreads();
    const float inv = invs[i];

    // feats row i: 16384-wide inv fill + normalized g
    {
        float4* f4 = (float4*)(feats + (size_t)i * FEATDIM);
        const float4 v = make_float4(inv, inv, inv, inv);
        f4[t] = v; f4[t + 1024] = v; f4[t + 2048] = v; f4[t + 3072] = v;
        if (t < TOKDIM) feats[(size_t)i * FEATDIM + LOCALDIM + t] = gT[t][i] * inv;
    }
    __syncthreads();

    {   // sim row i partials: gT[d][i] broadcast x gT[d][j] conflict-free
        const int q = t >> 6, j = t & 63;
        float s = 0.f;
        #pragma unroll
        for (int dd = 0; dd < 16; ++dd)
            s = fmaf(gT[q*16+dd][i], gT[q*16+dd][j], s);
        part[q][j] = s;
    }
    __syncthreads();
    if (t < BB) {                          // wave 0: full 64-lane wave
        float dot = 0.f;
        #pragma unroll
        for (int q = 0; q < 16; ++q) dot += part[q][t];
        const float sv = ((float)LOCALDIM + dot) * inv * invs[t];
        int k = *kptr; if (k > BB) k = BB;
        float v = sv;
        unsigned long long rowbits = 0;
        for (int p = 0; p < k; ++p) {      // ties -> lowest index (jax top_k)
            float m = v;
            #pragma unroll
            for (int off = 32; off > 0; off >>= 1) m = fmaxf(m, __shfl_xor(m, off));
            const unsigned long long ball = __ballot(v == m);
            const int bi = __ffsll(ball) - 1;
            rowbits |= 1ull << bi;
            if (t == bi) v = -INFINITY;
            if (t == 0) atomicOr(&maskU[bi * BB + i], ONEF);   // mask[idx, row] = 1
        }
        const unsigned base =
            ((sv > THRESH) || (t == i) || ((rowbits >> t) & 1ull)) ? ONEF : 0u;
        if (base) atomicOr(&maskU[i * BB + t], base);          // row i
    }
}

extern "C" void kernel_launch(void* const* d_in, const int* in_sizes, int n_in,
                              void* d_out, int out_size, void* d_ws, size_t ws_size,
                              hipStream_t stream) {
    const float* gtok = (const float*)d_in[1];
    const float* W1g  = (const float*)d_in[6];
    const float* b1g  = (const float*)d_in[7];
    const float* W2g  = (const float*)d_in[8];
    const float* b2g  = (const float*)d_in[9];
    const int*   kp   = (const int*)d_in[10];

    float*    feats = (float*)d_out;                              // [64, 16640]
    unsigned* maskU = (unsigned*)(feats + (size_t)BB * FEATDIM);  // [64,64] as bits
    float*    g     = (float*)d_ws;                               // [64][256] accum

    // zero the g accumulator (graph-legal memset node), then the two kernels
    hipMemsetAsync((void*)g, 0, (size_t)BB * TOKDIM * sizeof(float), stream);
    hipLaunchKernelGGL(kA, dim3(256), dim3(1024), 0, stream,
                       gtok, W1g, b1g, W2g, g, maskU);
    hipLaunchKernelGGL(kB, dim3(BB),  dim3(1024), 0, stream,
                       g, b2g, kp, feats, maskU);
}

// Round 14
// 20.377 us; speedup vs baseline: 1.1084x; 1.1084x over previous
//
#include <hip/hip_runtime.h>
#include <math.h>

#define TOKDIM   256
#define DD       768
#define HDIM     512
#define LOCALDIM 16384
#define FEATDIM  16640            // 16384 + 256
#define BB       64
#define THRESH   0.7f
#define ONEF     0x3f800000u      // bit pattern of 1.0f
#define GP       65               // gT LDS pad (stride 65: conflict-free rows+cols)

// NetVLAD local branch is identically 1.0 (softmax(axis=1).sum(axis=1) == 1),
// so feats = [inv * ones(16384), g/norm], norm = sqrt(16384 + ||g||^2), and
// sim_ij = (16384 + g_i.g_j) * inv_i * inv_j  (gn never materialized).

// ---- K1: 256 blocks = 64 batches x 4 unit-chunks of 128 h-units. ----
// Unit-split => full-d dot per unit => ReLU in-block => layer-2 partial g.
// Only the LINEAR g-sum crosses blocks (reduced redundantly in K2).
__global__ __launch_bounds__(1024) void k1_mlp(
    const float* __restrict__ gtok, const float* __restrict__ W1,
    const float* __restrict__ b1,   const float* __restrict__ W2,
    float* __restrict__ pg,         unsigned* __restrict__ maskU)
{
    __shared__ float  xs[DD];
    __shared__ float4 hh4[32][32];    // layer-1 partials: [d-slice][unit-quad]
    __shared__ float  hs[128];
    __shared__ float4 gg4[16][64];    // layer-2 partials: [unit-slice][out-quad]
    const int blk = blockIdx.x, t = threadIdx.x;
    const int b = blk >> 2, uc = blk & 3;

    if (blk == 0) {                   // zero mask; graph edge orders before K2
        maskU[t] = 0u; maskU[t + 1024] = 0u; maskU[t + 2048] = 0u; maskU[t + 3072] = 0u;
    }
    if (t < DD) xs[t] = gtok[b * DD + t];
    __syncthreads();

    // layer 1: thread = 4 units (float4) x 24-d slice -> 3 unroll-8 groups
    {
        const int u4 = t & 31, q = t >> 5;
        const float4* w = (const float4*)W1 + (size_t)(q * 24) * 128 + uc * 32 + u4;
        float4 a = make_float4(0.f, 0.f, 0.f, 0.f);
        #pragma unroll 8
        for (int d = 0; d < 24; ++d) {
            const float x = xs[q * 24 + d];
            const float4 wv = w[(size_t)d * 128];
            a.x = fmaf(x, wv.x, a.x); a.y = fmaf(x, wv.y, a.y);
            a.z = fmaf(x, wv.z, a.z); a.w = fmaf(x, wv.w, a.w);
        }
        hh4[q][u4] = a;
    }
    __syncthreads();
    if (t < 128) {
        const float* h = (const float*)hh4;
        float s = b1[uc * 128 + t];
        #pragma unroll
        for (int q = 0; q < 32; ++q) s += h[q * 128 + t];
        hs[t] = fmaxf(s, 0.f);        // ReLU on COMPLETE h (full 768-d dot)
    }
    __syncthreads();

    // layer 2 partial: thread = 4 outputs (float4) x 8-unit slice -> 1 group
    {
        const int o4 = t & 63, jq = t >> 6;
        const float4* w = (const float4*)W2 + (size_t)(uc * 128 + jq * 8) * 64 + o4;
        float4 a = make_float4(0.f, 0.f, 0.f, 0.f);
        #pragma unroll
        for (int j = 0; j < 8; ++j) {
            const float hv = hs[jq * 8 + j];
            const float4 wv = w[(size_t)j * 64];
            a.x = fmaf(hv, wv.x, a.x); a.y = fmaf(hv, wv.y, a.y);
            a.z = fmaf(hv, wv.z, a.z); a.w = fmaf(hv, wv.w, a.w);
        }
        gg4[jq][o4] = a;
    }
    __syncthreads();
    if (t < 256) {
        const float* g = (const float*)gg4;
        float s = 0.f;
        #pragma unroll
        for (int q = 0; q < 16; ++q) s += g[q * 256 + t];
        pg[((size_t)uc * BB + b) * TOKDIM + t] = s;   // [uc][b][256]
    }
}

// ---- K2: 64 blocks. Block i: full g-reduce for ALL batches (256 KB, L2-hot),
// all inv-norms, feats row i, sim row i, top-k, idempotent mask ORs. ----
__global__ __launch_bounds__(1024) void k2_simmask(
    const float* __restrict__ pg, const float* __restrict__ b2,
    const int* __restrict__ kptr, float* __restrict__ feats,
    unsigned* __restrict__ maskU)
{
    __shared__ float gT[TOKDIM][GP];   // g transposed, padded
    __shared__ float part[16][BB];
    __shared__ float invs[BB];
    const int i = blockIdx.x, t = threadIdx.x;

    // reduce g for all 64 batches: 16 iters x 1024 coalesced 4-way loads
    #pragma unroll
    for (int it = 0; it < 16; ++it) {
        const int idx = it * 1024 + t;
        const int j = idx >> 8, d = idx & 255;
        const float v = b2[d]
            + pg[((size_t)0 * BB + j) * TOKDIM + d]
            + pg[((size_t)1 * BB + j) * TOKDIM + d]
            + pg[((size_t)2 * BB + j) * TOKDIM + d]
            + pg[((size_t)3 * BB + j) * TOKDIM + d];
        gT[d][j] = v;
    }
    __syncthreads();

    // ||g_j||^2 partials -> inv norms
    {
        const int q = t >> 6, j = t & 63;
        float s = 0.f;
        #pragma unroll
        for (int dd = 0; dd < 16; ++dd) { const float v = gT[q * 16 + dd][j]; s = fmaf(v, v, s); }
        part[q][j] = s;
    }
    __syncthreads();
    if (t < BB) {
        float ssq = 0.f;
        #pragma unroll
        for (int q = 0; q < 16; ++q) ssq += part[q][t];
        invs[t] = 1.f / fmaxf(sqrtf((float)LOCALDIM + ssq), 1e-12f);
    }
    __syncthreads();
    const float inv = invs[i];

    // feats row i: 16384-wide inv fill (4 float4/thread) + normalized g
    {
        float4* f4 = (float4*)(feats + (size_t)i * FEATDIM);
        const float4 v = make_float4(inv, inv, inv, inv);
        f4[t] = v; f4[t + 1024] = v; f4[t + 2048] = v; f4[t + 3072] = v;
        if (t < TOKDIM) feats[(size_t)i * FEATDIM + LOCALDIM + t] = gT[t][i] * inv;
    }

    // sim row i partials: gT[d][i] broadcast, gT[d][j] stride-1 (2/bank, free)
    {
        const int q = t >> 6, j = t & 63;
        float s = 0.f;
        #pragma unroll
        for (int dd = 0; dd < 16; ++dd)
            s = fmaf(gT[q * 16 + dd][i], gT[q * 16 + dd][j], s);
        part[q][j] = s;
    }
    __syncthreads();
    if (t < BB) {                      // wave 0: full 64-lane wave
        float dot = 0.f;
        #pragma unroll
        for (int q = 0; q < 16; ++q) dot += part[q][t];
        const float sv = ((float)LOCALDIM + dot) * inv * invs[t];
        int k = *kptr; if (k > BB) k = BB;
        float v = sv;
        unsigned long long rowbits = 0;
        for (int p = 0; p < k; ++p) {  // ties -> lowest index (jax top_k)
            float m = v;
            #pragma unroll
            for (int off = 32; off > 0; off >>= 1) m = fmaxf(m, __shfl_xor(m, off));
            const unsigned long long ball = __ballot(v == m);
            const int bi = __ffsll(ball) - 1;
            rowbits |= 1ull << bi;
            if (t == bi) v = -INFINITY;
            if (t == 0) atomicOr(&maskU[bi * BB + i], ONEF);   // mask[idx, row] = 1
        }
        const unsigned base =
            ((sv > THRESH) || (t == i) || ((rowbits >> t) & 1ull)) ? ONEF : 0u;
        if (base) atomicOr(&maskU[i * BB + t], base);          // row i
    }
}

extern "C" void kernel_launch(void* const* d_in, const int* in_sizes, int n_in,
                              void* d_out, int out_size, void* d_ws, size_t ws_size,
                              hipStream_t stream) {
    const float* gtok = (const float*)d_in[1];
    const float* W1g  = (const float*)d_in[6];
    const float* b1g  = (const float*)d_in[7];
    const float* W2g  = (const float*)d_in[8];
    const float* b2g  = (const float*)d_in[9];
    const int*   kp   = (const int*)d_in[10];

    float*    feats = (float*)d_out;                              // [64, 16640]
    unsigned* maskU = (unsigned*)(feats + (size_t)BB * FEATDIM);  // [64,64] as bits
    float*    pg    = (float*)d_ws;                               // [4][64][256]

    hipLaunchKernelGGL(k1_mlp,     dim3(256), dim3(1024), 0, stream,
                       gtok, W1g, b1g, W2g, pg, maskU);
    hipLaunchKernelGGL(k2_simmask, dim3(BB),  dim3(1024), 0, stream,
                       pg, b2g, kp, feats, maskU);
}